// Round 7
// baseline (171.804 us; speedup 1.0000x reference)
//
#include <hip/hip_runtime.h>
#include <math.h>

#define BB 64
#define LL 1024
#define HH 256
#define TT 128
#define D_ID 128
#define D_SZ 64
#define D_POS 128
#define DX 192   // D_ID + D_SZ

typedef short s16x8 __attribute__((ext_vector_type(8)));
typedef float f32x16 __attribute__((ext_vector_type(16)));
typedef unsigned short u16x8 __attribute__((ext_vector_type(8)));
typedef unsigned short u16x4 __attribute__((ext_vector_type(4)));

__device__ __forceinline__ unsigned short f2bf(float f) {
    unsigned u = __float_as_uint(f);
    unsigned r = u + 0x7fffu + ((u >> 16) & 1u);   // RNE
    return (unsigned short)(r >> 16);
}

__device__ __forceinline__ s16x8 pack8(float4 a, float4 b) {
    u16x8 p;
    p[0] = f2bf(a.x); p[1] = f2bf(a.y); p[2] = f2bf(a.z); p[3] = f2bf(a.w);
    p[4] = f2bf(b.x); p[5] = f2bf(b.y); p[6] = f2bf(b.z); p[7] = f2bf(b.w);
    return (s16x8)p;
}

// ============================== N1: embed + bf16 converts (all streaming)
//   [0,112):          xh_t[448][64] = concat(x, h0)^T    (R0 embed)
//   [112,4208):       obj_id_table -> qT bf16 (48 MB, coalesced, R6 form)
//   [4208,5224):      history -> histB bf16 (12.5 MB)
//   [5224,5240):      attn_W -> attnWB bf16
__global__ void embed_kernel(const int* __restrict__ obj_id,
                             const int* __restrict__ obj_size,
                             const float* __restrict__ h0,
                             const float* __restrict__ obj_id_table,
                             const float* __restrict__ obj_size_table,
                             const float* __restrict__ history,
                             const float* __restrict__ attn_W,
                             float* __restrict__ xh_t,
                             unsigned short* __restrict__ qT,
                             unsigned short* __restrict__ histB,
                             unsigned short* __restrict__ attnWB) {
    int blk = blockIdx.x;
    int tid = threadIdx.x;

    if (blk < 112) {
        int b = tid & 63;
        int k = blk * 4 + (tid >> 6);
        float v;
        if (k < D_ID)      v = obj_id_table[(size_t)obj_id[b] * D_ID + k];
        else if (k < DX)   v = obj_size_table[(size_t)obj_size[b] * D_SZ + (k - D_ID)];
        else               v = h0[b * HH + (k - DX)];
        xh_t[k * 64 + b] = v;
        return;
    }
    if (blk < 4208) {
        size_t g = ((size_t)(blk - 112) * 256 + tid) * 8;
        float4 a = *(const float4*)(obj_id_table + g);
        float4 b = *(const float4*)(obj_id_table + g + 4);
        *(s16x8*)(qT + g) = pack8(a, b);
        return;
    }
    if (blk < 5224) {
        size_t g = ((size_t)(blk - 4208) * 256 + tid) * 8;
        float4 a = *(const float4*)(history + g);
        float4 b = *(const float4*)(history + g + 4);
        *(s16x8*)(histB + g) = pack8(a, b);
        return;
    }
    {
        size_t g = ((size_t)(blk - 5224) * 256 + tid) * 8;
        float4 a = *(const float4*)(attn_W + g);
        float4 b = *(const float4*)(attn_W + g + 4);
        *(s16x8*)(attnWB + g) = pack8(a, b);
    }
}

// --------------- gates + fused LSTM activation (R0) + bf16 h_new copy
__global__ void gates_kernel(const float* __restrict__ xh_t,
                             const float* __restrict__ W_ih,
                             const float* __restrict__ W_hh,
                             const float* __restrict__ b_ih,
                             const float* __restrict__ b_hh,
                             const float* __restrict__ c0,
                             float* __restrict__ h_new,
                             unsigned short* __restrict__ hnewB) {
    int j = blockIdx.x;
    int tid = threadIdx.x;
    int b = tid & 63;
    int q = __builtin_amdgcn_readfirstlane(tid >> 6);
    int r = q * HH + j;
    __shared__ float gS[256];

    float acc = b_ih[r] + b_hh[r];
    const float* wi = W_ih + (size_t)r * DX;
    const float* wh = W_hh + (size_t)r * HH;
#pragma unroll 16
    for (int k = 0; k < DX; ++k)
        acc += wi[k] * xh_t[k * 64 + b];
#pragma unroll 16
    for (int k = 0; k < HH; ++k)
        acc += wh[k] * xh_t[(DX + k) * 64 + b];
    gS[q * 64 + b] = acc;
    __syncthreads();

    if (tid < 64) {
        float ig = 1.f / (1.f + expf(-gS[tid]));
        float fg = 1.f / (1.f + expf(-gS[64 + tid]));
        float gg = tanhf(gS[128 + tid]);
        float og = 1.f / (1.f + expf(-gS[192 + tid]));
        float c = fg * c0[tid * HH + j] + ig * gg;
        float h = og * tanhf(c);
        h_new[tid * HH + j] = h;
        hnewB[tid * HH + j] = f2bf(h);
    }
}

// ------------- proj: hpF = (hist @ attn_W^T) in FRAGMENT-MAJOR bf16 layout
// Blocks [0,256): (b,tt) tile; 4 waves = 4 d-quarters. SWAPPED orientation
// (A=attn_W rows M=d, B=hist rows N=t, verified R1/R2): lane holds 16
// d-values for one t -> u16x4 quad-stores straight into the score-MFMA
// fragment layout hpF[b][k][tt][lane][8]. bf16 sources -> zero pack VALU.
// Blocks [256,320): svrv dots (fp32, unchanged math), all t incl 127.
__global__ void proj_kernel(const unsigned short* __restrict__ histB,
                            const unsigned short* __restrict__ hnewB,
                            const float* __restrict__ history,
                            const float* __restrict__ h_new,
                            const unsigned short* __restrict__ attnWB,
                            const float* __restrict__ pos_table,
                            const float* __restrict__ scorer_W,
                            const float* __restrict__ reuse_W,
                            unsigned short* __restrict__ hpF,
                            float* __restrict__ sv,
                            float* __restrict__ rv) {
    int blk = blockIdx.x;
    int tid = threadIdx.x;

    if (blk >= 256) {
        // ---- svrv: b = blk-256; which = tid>>7, t = tid&127
        int b = blk - 256;
        int which = tid >> 7;
        int t = tid & 127;
        const float* w = which ? reuse_W : scorer_W;
        const float* hrow = (t < TT - 1)
            ? history + ((size_t)b * (TT - 1) + t) * HH
            : h_new + (size_t)b * HH;
        float acc = 0.f;
#pragma unroll 8
        for (int k = 0; k < HH / 4; ++k) {
            float4 hv = *(const float4*)(hrow + 4 * k);
            float4 wv = *(const float4*)(w + 4 * k);
            acc += hv.x * wv.x + hv.y * wv.y + hv.z * wv.z + hv.w * wv.w;
        }
        const float* prow = pos_table + (size_t)t * D_POS;
#pragma unroll 8
        for (int k = 0; k < D_POS / 4; ++k) {
            float4 pv = *(const float4*)(prow + 4 * k);
            float4 wv = *(const float4*)(w + HH + 4 * k);
            acc += pv.x * wv.x + pv.y * wv.y + pv.z * wv.z + pv.w * wv.w;
        }
        (which ? rv : sv)[b * TT + t] = acc;
        return;
    }

    // ---- proj tile (b, tt), wave w -> d0 = 32w
    int b  = blk >> 2;
    int tt = blk & 3;
    int w  = tid >> 6;
    int lane = tid & 63;
    int ln = lane & 31, half = lane >> 5;

    int t = tt * 32 + ln;
    const unsigned short* arow = attnWB + (size_t)(32 * w + ln) * HH;   // A: d-row
    const unsigned short* brow = (t < TT - 1)                            // B: t-row
        ? histB + ((size_t)b * (TT - 1) + t) * HH
        : hnewB + (size_t)b * HH;

    f32x16 acc;
#pragma unroll
    for (int r = 0; r < 16; ++r) acc[r] = 0.f;

#pragma unroll
    for (int ks = 0; ks < 16; ++ks) {
        int off = ks * 16 + half * 8;
        s16x8 af = *(const s16x8*)(arow + off);
        s16x8 bf = *(const s16x8*)(brow + off);
        acc = __builtin_amdgcn_mfma_f32_32x32x16_bf16(af, bf, acc, 0, 0, 0);
    }

    // C: d = 32w + (r&3)+8*(r>>2)+4*half, t-col = ln. Quad-store into
    // hpF frag (k' = 2w + (qd>>1), tt, lane' = (ln, half'=qd&1), j0=4*half).
    unsigned short* hb = hpF + (size_t)b * 16384;
#pragma unroll
    for (int qd = 0; qd < 4; ++qd) {
        u16x4 v;
        v[0] = f2bf(acc[4 * qd + 0]);
        v[1] = f2bf(acc[4 * qd + 1]);
        v[2] = f2bf(acc[4 * qd + 2]);
        v[3] = f2bf(acc[4 * qd + 3]);
        int sa = ((2 * w + (qd >> 1)) * 4 + tt) * 512 +
                 (qd & 1) * 256 + ln * 8 + 4 * half;
        *(u16x4*)(hb + sa) = v;
    }
}

// ---- attn: coalesced hpF frags + SWAPPED score MFMA + shuffle-free softmax
// mfma(bf, qf): identical fragment bytes, C transposed -> lane owns
// l = l0+ln and 64 t-values in regs. Softmax = local reduce + 2 shfls;
// logits store is one coalesced 32-lane store.
__global__ void __launch_bounds__(64)
attn_kernel(const int* __restrict__ cache_lines,
            const unsigned short* __restrict__ qT,
            const unsigned short* __restrict__ hpF,
            const float* __restrict__ sv,
            const float* __restrict__ rv,
            const float* __restrict__ scorer_b,
            const float* __restrict__ reuse_b,
            float* __restrict__ logits,
            float* __restrict__ out_reuse) {
    int b  = blockIdx.x >> 5;
    int l0 = (blockIdx.x & 31) * 32;
    int lane = threadIdx.x;
    int ln = lane & 31, half = lane >> 5;

    // ---- Q gather -> registers (issued first)
    int cl = cache_lines[b * LL + l0 + ln];
    const unsigned short* qrow = qT + (size_t)cl * D_ID + half * 8;
    s16x8 qf[8];
#pragma unroll
    for (int ks = 0; ks < 8; ++ks)
        qf[ks] = *(const s16x8*)(qrow + ks * 16);

    float sb = scorer_b[0], rb = reuse_b[0];

    // ---- scores^T: acc[tt][r] = score[t = tt*32 + crow(r,half)][l = l0+ln]
    const s16x8* hpb = (const s16x8*)(hpF) + (size_t)b * 2048;
    f32x16 acc[4];
#pragma unroll
    for (int tt = 0; tt < 4; ++tt)
#pragma unroll
        for (int r = 0; r < 16; ++r) acc[tt][r] = 0.f;

#pragma unroll
    for (int k = 0; k < 8; ++k) {
#pragma unroll
        for (int tt = 0; tt < 4; ++tt) {
            s16x8 bf = hpb[(k * 4 + tt) * 64 + lane];   // coalesced
            acc[tt] = __builtin_amdgcn_mfma_f32_32x32x16_bf16(bf, qf[k], acc[tt], 0, 0, 0);
        }
    }

    // ---- softmax over t (this lane holds 64 of 128 t's; partner = lane^32)
    float m = -1e30f;
#pragma unroll
    for (int tt = 0; tt < 4; ++tt)
#pragma unroll
        for (int r = 0; r < 16; ++r) m = fmaxf(m, acc[tt][r]);
    m = fmaxf(m, __shfl_xor(m, 32));

    float s = 0.f, lg = 0.f, rg = 0.f;
#pragma unroll
    for (int tt = 0; tt < 4; ++tt) {
#pragma unroll
        for (int q = 0; q < 4; ++q) {
            // t = tt*32 + 8q + 4*half + i  <->  acc[tt][4q+i]
            const float4 s4 = *(const float4*)(sv + b * TT + tt * 32 + 8 * q + 4 * half);
            const float4 r4 = *(const float4*)(rv + b * TT + tt * 32 + 8 * q + 4 * half);
            float e0 = __expf(acc[tt][4 * q + 0] - m);
            float e1 = __expf(acc[tt][4 * q + 1] - m);
            float e2 = __expf(acc[tt][4 * q + 2] - m);
            float e3 = __expf(acc[tt][4 * q + 3] - m);
            s  += e0 + e1 + e2 + e3;
            lg += e0 * s4.x + e1 * s4.y + e2 * s4.z + e3 * s4.w;
            rg += e0 * r4.x + e1 * r4.y + e2 * r4.z + e3 * r4.w;
        }
    }
    s  += __shfl_xor(s, 32);
    lg += __shfl_xor(lg, 32);
    rg += __shfl_xor(rg, 32);

    if (half == 0) {
        logits[b * LL + l0 + ln] = lg / s + sb;
        out_reuse[b * LL + l0 + ln] = rg / s + rb;
    }
}

// -------------------------------------- masked softmax over L per batch
__global__ void finalsm_kernel(const float* __restrict__ logits,
                               const int* __restrict__ lengths,
                               float* __restrict__ out_probs) {
    int b = blockIdx.x;
    int tid = threadIdx.x;
    int valid = max(lengths[b], 1);
    float v[4];
    float m = -1e30f;
#pragma unroll
    for (int i = 0; i < 4; ++i) {
        int l = tid + 256 * i;
        v[i] = (l < valid) ? logits[b * LL + l] : -1e30f;
        m = fmaxf(m, v[i]);
    }
#pragma unroll
    for (int off = 1; off < 64; off <<= 1) m = fmaxf(m, __shfl_xor(m, off));
    __shared__ float redm[4];
    __shared__ float reds[4];
    int wave = tid >> 6;
    if ((tid & 63) == 0) redm[wave] = m;
    __syncthreads();
    m = fmaxf(fmaxf(redm[0], redm[1]), fmaxf(redm[2], redm[3]));
    float e[4];
    float s = 0.f;
#pragma unroll
    for (int i = 0; i < 4; ++i) {
        int l = tid + 256 * i;
        e[i] = (l < valid) ? expf(v[i] - m) : 0.f;
        s += e[i];
    }
#pragma unroll
    for (int off = 1; off < 64; off <<= 1) s += __shfl_xor(s, off);
    if ((tid & 63) == 0) reds[wave] = s;
    __syncthreads();
    s = reds[0] + reds[1] + reds[2] + reds[3];
    float inv = 1.f / s;
#pragma unroll
    for (int i = 0; i < 4; ++i)
        out_probs[b * LL + tid + 256 * i] = e[i] * inv;
}

extern "C" void kernel_launch(void* const* d_in, const int* in_sizes, int n_in,
                              void* d_out, int out_size, void* d_ws, size_t ws_size,
                              hipStream_t stream) {
    const int*   obj_id         = (const int*)d_in[0];
    const int*   obj_size       = (const int*)d_in[1];
    const int*   cache_lines    = (const int*)d_in[2];
    const int*   lengths        = (const int*)d_in[3];
    const float* c0             = (const float*)d_in[4];
    const float* h0             = (const float*)d_in[5];
    const float* history        = (const float*)d_in[6];
    const float* obj_id_table   = (const float*)d_in[7];
    const float* obj_size_table = (const float*)d_in[8];
    const float* pos_table      = (const float*)d_in[9];
    const float* W_ih           = (const float*)d_in[10];
    const float* W_hh           = (const float*)d_in[11];
    const float* b_ih           = (const float*)d_in[12];
    const float* b_hh           = (const float*)d_in[13];
    const float* attn_W         = (const float*)d_in[14];
    const float* scorer_W       = (const float*)d_in[15];
    const float* scorer_b       = (const float*)d_in[16];
    const float* reuse_W        = (const float*)d_in[17];
    const float* reuse_b        = (const float*)d_in[18];

    float* out = (float*)d_out;
    float* out_probs = out;                 // (B, L)
    float* out_reuse = out + BB * LL;       // (B, L)

    char* ws = (char*)d_ws;
    float*          h_new  = (float*)(ws);                      // 64 KB
    unsigned short* hpF    = (unsigned short*)(ws + 65536);     // 2 MB bf16 (frag-major)
    float*          sv     = (float*)(ws + 2162688);            // 32 KB
    float*          rv     = (float*)(ws + 2195456);            // 32 KB
    float*          xh_t   = (float*)(ws + 2228224);            // 112 KB
    float*          logits = (float*)(ws + 2228224);            // shares xh_t (disjoint lifetime)
    unsigned short* qT     = (unsigned short*)(ws + 4194304);   // 16 MB
    unsigned short* histB  = (unsigned short*)(ws + 20971520);  // ~4 MB
    unsigned short* attnWB = (unsigned short*)(ws + 25165824);  // 64 KB
    unsigned short* hnewB  = (unsigned short*)(ws + 25231360);  // 32 KB

    // N1: embed + bf16 converts (qT, histB, attnWB)
    hipLaunchKernelGGL(embed_kernel, dim3(5240), dim3(256), 0, stream,
                       obj_id, obj_size, h0, obj_id_table, obj_size_table,
                       history, attn_W, xh_t, qT, histB, attnWB);
    // N2: gates (+ hnewB)
    hipLaunchKernelGGL(gates_kernel, dim3(HH), dim3(256), 0, stream,
                       xh_t, W_ih, W_hh, b_ih, b_hh, c0, h_new, hnewB);
    // N3: proj -> fragment-major hpF (bf16 sources) + svrv
    hipLaunchKernelGGL(proj_kernel, dim3(320), dim3(256), 0, stream,
                       histB, hnewB, history, h_new, attnWB, pos_table,
                       scorer_W, reuse_W, hpF, sv, rv);
    // N4: attn (coalesced hpF + swapped MFMA + shuffle-free softmax)
    hipLaunchKernelGGL(attn_kernel, dim3(BB * 32), dim3(64), 0, stream,
                       cache_lines, qT, hpF, sv, rv,
                       scorer_b, reuse_b, logits, out_reuse);
    // N5: masked softmax
    hipLaunchKernelGGL(finalsm_kernel, dim3(BB), dim3(256), 0, stream,
                       logits, lengths, out_probs);
}

// Round 8
// 162.991 us; speedup vs baseline: 1.0541x; 1.0541x over previous
//
#include <hip/hip_runtime.h>
#include <math.h>

#define BB 64
#define LL 1024
#define HH 256
#define TT 128
#define D_ID 128
#define D_SZ 64
#define D_POS 128
#define DX 192   // D_ID + D_SZ

typedef short s16x8 __attribute__((ext_vector_type(8)));
typedef float f32x16 __attribute__((ext_vector_type(16)));
typedef unsigned short u16x8 __attribute__((ext_vector_type(8)));
typedef unsigned short u16x4 __attribute__((ext_vector_type(4)));

__device__ __forceinline__ unsigned short f2bf(float f) {
    unsigned u = __float_as_uint(f);
    unsigned r = u + 0x7fffu + ((u >> 16) & 1u);   // RNE
    return (unsigned short)(r >> 16);
}

__device__ __forceinline__ s16x8 pack8(float4 a, float4 b) {
    u16x8 p;
    p[0] = f2bf(a.x); p[1] = f2bf(a.y); p[2] = f2bf(a.z); p[3] = f2bf(a.w);
    p[4] = f2bf(b.x); p[5] = f2bf(b.y); p[6] = f2bf(b.z); p[7] = f2bf(b.w);
    return (s16x8)p;
}

// ------------------------------------------- xh_t[448][64] = concat(x, h0)^T
__global__ void embed_kernel(const int* __restrict__ obj_id,
                             const int* __restrict__ obj_size,
                             const float* __restrict__ h0,
                             const float* __restrict__ obj_id_table,
                             const float* __restrict__ obj_size_table,
                             float* __restrict__ xh_t) {
    int tid = threadIdx.x;
    int b = tid & 63;
    int k = blockIdx.x * 4 + (tid >> 6);
    float v;
    if (k < D_ID)      v = obj_id_table[(size_t)obj_id[b] * D_ID + k];
    else if (k < DX)   v = obj_size_table[(size_t)obj_size[b] * D_SZ + (k - D_ID)];
    else               v = h0[b * HH + (k - DX)];
    xh_t[k * 64 + b] = v;
}

// --------------- gates + fused LSTM activation (R0, unchanged)
__global__ void gates_kernel(const float* __restrict__ xh_t,
                             const float* __restrict__ W_ih,
                             const float* __restrict__ W_hh,
                             const float* __restrict__ b_ih,
                             const float* __restrict__ b_hh,
                             const float* __restrict__ c0,
                             float* __restrict__ h_new) {
    int j = blockIdx.x;
    int tid = threadIdx.x;
    int b = tid & 63;
    int q = __builtin_amdgcn_readfirstlane(tid >> 6);
    int r = q * HH + j;
    __shared__ float gS[256];

    float acc = b_ih[r] + b_hh[r];
    const float* wi = W_ih + (size_t)r * DX;
    const float* wh = W_hh + (size_t)r * HH;
#pragma unroll 16
    for (int k = 0; k < DX; ++k)
        acc += wi[k] * xh_t[k * 64 + b];
#pragma unroll 16
    for (int k = 0; k < HH; ++k)
        acc += wh[k] * xh_t[(DX + k) * 64 + b];
    gS[q * 64 + b] = acc;
    __syncthreads();

    if (tid < 64) {
        float ig = 1.f / (1.f + expf(-gS[tid]));
        float fg = 1.f / (1.f + expf(-gS[64 + tid]));
        float gg = tanhf(gS[128 + tid]);
        float og = 1.f / (1.f + expf(-gS[192 + tid]));
        float c = fg * c0[tid * HH + j] + ig * gg;
        h_new[tid * HH + j] = og * tanhf(c);
    }
}

// =====================================================================
// N3: qgather ∥ proj ∥ svrv in ONE grid (all 64-thr blocks).
//   [0,2048):    Q-GATHER: tile = b*32+ltile; lane (ln,half) gathers
//     row cl=cache_lines[...l0+ln] from the fp32 table, pack8 (same RNE
//     bytes as ever), coalesced 16B stores into fragment-ordered
//     qG[tile][ks][lane][8]. 2048 latency-heavy waves issued FIRST...
//   [2048,3072): ...overlap proj: swapped orientation (A=attn_W d-rows,
//     B=hist t-rows; verified R1/R7), fp32+pack8 sources (R0 cost),
//     u16x4 quad-stores into frag-major hpF[b][k][tt][lane][8] (R7
//     formula, verified).
//   [3072,3328): svrv dots (R0 code).
//   Gather and proj mutually hide each other's ~900cy HBM stalls:
//   ~13 waves/CU combined vs 5 (proj) then 8 (attn gather) serialized.
// =====================================================================
__global__ void proj_kernel(const int* __restrict__ cache_lines,
                            const float* __restrict__ obj_id_table,
                            const float* __restrict__ history,
                            const float* __restrict__ h_new,
                            const float* __restrict__ attn_W,
                            const float* __restrict__ pos_table,
                            const float* __restrict__ scorer_W,
                            const float* __restrict__ reuse_W,
                            unsigned short* __restrict__ qG,
                            unsigned short* __restrict__ hpF,
                            float* __restrict__ sv,
                            float* __restrict__ rv) {
    int blk = blockIdx.x;
    int tid = threadIdx.x;

    if (blk < 2048) {
        // ---- Q-gather -> qG (fragment order)
        int tile = blk;
        int b = tile >> 5, l0 = (tile & 31) * 32;
        int ln = tid & 31, half = tid >> 5;
        int cl = cache_lines[b * LL + l0 + ln];
        const float* qrow = obj_id_table + (size_t)cl * D_ID;
        unsigned short* dst = qG + (size_t)tile * 4096;
#pragma unroll
        for (int ks = 0; ks < 8; ++ks) {
            float4 a = *(const float4*)(qrow + ks * 16 + half * 8);
            float4 c = *(const float4*)(qrow + ks * 16 + half * 8 + 4);
            *(s16x8*)(dst + (ks * 64 + tid) * 8) = pack8(a, c);
        }
        return;
    }

    if (blk < 3072) {
        // ---- proj tile: p = (b, w, tt); wave computes d-rows [32w,+32)
        // x t-cols [32tt,+32), C quads -> frag-major hpF.
        int p = blk - 2048;
        int b  = p >> 4;
        int w  = (p >> 2) & 3;
        int tt = p & 3;
        int ln = tid & 31, half = tid >> 5;

        int t = tt * 32 + ln;
        const float* arow = attn_W + (size_t)(32 * w + ln) * HH;
        const float* brow = (t < TT - 1)
            ? history + ((size_t)b * (TT - 1) + t) * HH
            : h_new + (size_t)b * HH;

        f32x16 acc;
#pragma unroll
        for (int r = 0; r < 16; ++r) acc[r] = 0.f;

#pragma unroll
        for (int ks = 0; ks < 16; ++ks) {
            int off = ks * 16 + half * 8;
            float4 a0 = *(const float4*)(arow + off);
            float4 a1 = *(const float4*)(arow + off + 4);
            float4 b0 = *(const float4*)(brow + off);
            float4 b1 = *(const float4*)(brow + off + 4);
            acc = __builtin_amdgcn_mfma_f32_32x32x16_bf16(
                pack8(a0, a1), pack8(b0, b1), acc, 0, 0, 0);
        }

        unsigned short* hb = hpF + (size_t)b * 16384;
#pragma unroll
        for (int qd = 0; qd < 4; ++qd) {
            u16x4 v;
            v[0] = f2bf(acc[4 * qd + 0]);
            v[1] = f2bf(acc[4 * qd + 1]);
            v[2] = f2bf(acc[4 * qd + 2]);
            v[3] = f2bf(acc[4 * qd + 3]);
            int sa = ((2 * w + (qd >> 1)) * 4 + tt) * 512 +
                     (qd & 1) * 256 + ln * 8 + 4 * half;
            *(u16x4*)(hb + sa) = v;
        }
        return;
    }

    // ---- svrv (R0): idx = b*4 + which*2 + thalf
    {
        int idx = blk - 3072;
        int b = idx >> 2;
        int which = (idx >> 1) & 1;
        int t = (idx & 1) * 64 + tid;
        const float* w = which ? reuse_W : scorer_W;
        const float* hrow = (t < TT - 1)
            ? history + ((size_t)b * (TT - 1) + t) * HH
            : h_new + (size_t)b * HH;
        float acc = 0.f;
#pragma unroll 8
        for (int k = 0; k < HH / 4; ++k) {
            float4 hv = *(const float4*)(hrow + 4 * k);
            float4 wv = *(const float4*)(w + 4 * k);
            acc += hv.x * wv.x + hv.y * wv.y + hv.z * wv.z + hv.w * wv.w;
        }
        const float* prow = pos_table + (size_t)t * D_POS;
#pragma unroll 8
        for (int k = 0; k < D_POS / 4; ++k) {
            float4 pv = *(const float4*)(prow + 4 * k);
            float4 wv = *(const float4*)(w + HH + 4 * k);
            acc += pv.x * wv.x + pv.y * wv.y + pv.z * wv.z + pv.w * wv.w;
        }
        (which ? rv : sv)[b * TT + t] = acc;
    }
}

// ---- attn: PURE STREAMING. qf frags coalesced from qG (L2/L3-warm,
// written by N3), hp frags coalesced from frag-major hpF. Swapped MFMA
// (C transposed: lane owns l = l0+ln, 64 t-values) + R7 shuffle-free
// softmax (2 shfls) + coalesced store. No random access left.
__global__ void __launch_bounds__(64)
attn_kernel(const unsigned short* __restrict__ qG,
            const unsigned short* __restrict__ hpF,
            const float* __restrict__ sv,
            const float* __restrict__ rv,
            const float* __restrict__ scorer_b,
            const float* __restrict__ reuse_b,
            float* __restrict__ logits,
            float* __restrict__ out_reuse) {
    int tile = blockIdx.x;
    int b  = tile >> 5;
    int l0 = (tile & 31) * 32;
    int lane = threadIdx.x;
    int ln = lane & 31, half = lane >> 5;

    // ---- Q frags: coalesced reads from staging
    const s16x8* qsrc = (const s16x8*)(qG) + (size_t)tile * 512;
    s16x8 qf[8];
#pragma unroll
    for (int ks = 0; ks < 8; ++ks)
        qf[ks] = qsrc[ks * 64 + lane];

    float sb = scorer_b[0], rb = reuse_b[0];

    // ---- scores^T: acc[tt][r] = score[t = tt*32 + crow(r,half)][l = l0+ln]
    const s16x8* hpb = (const s16x8*)(hpF) + (size_t)b * 2048;
    f32x16 acc[4];
#pragma unroll
    for (int tt = 0; tt < 4; ++tt)
#pragma unroll
        for (int r = 0; r < 16; ++r) acc[tt][r] = 0.f;

#pragma unroll
    for (int k = 0; k < 8; ++k) {
#pragma unroll
        for (int tt = 0; tt < 4; ++tt) {
            s16x8 bf = hpb[(k * 4 + tt) * 64 + lane];   // coalesced
            acc[tt] = __builtin_amdgcn_mfma_f32_32x32x16_bf16(bf, qf[k], acc[tt], 0, 0, 0);
        }
    }

    // ---- softmax over t (lane holds 64 of 128 t's; partner = lane^32)
    float m = -1e30f;
#pragma unroll
    for (int tt = 0; tt < 4; ++tt)
#pragma unroll
        for (int r = 0; r < 16; ++r) m = fmaxf(m, acc[tt][r]);
    m = fmaxf(m, __shfl_xor(m, 32));

    float s = 0.f, lg = 0.f, rg = 0.f;
#pragma unroll
    for (int tt = 0; tt < 4; ++tt) {
#pragma unroll
        for (int q = 0; q < 4; ++q) {
            // t = tt*32 + 8q + 4*half + i  <->  acc[tt][4q+i]
            const float4 s4 = *(const float4*)(sv + b * TT + tt * 32 + 8 * q + 4 * half);
            const float4 r4 = *(const float4*)(rv + b * TT + tt * 32 + 8 * q + 4 * half);
            float e0 = __expf(acc[tt][4 * q + 0] - m);
            float e1 = __expf(acc[tt][4 * q + 1] - m);
            float e2 = __expf(acc[tt][4 * q + 2] - m);
            float e3 = __expf(acc[tt][4 * q + 3] - m);
            s  += e0 + e1 + e2 + e3;
            lg += e0 * s4.x + e1 * s4.y + e2 * s4.z + e3 * s4.w;
            rg += e0 * r4.x + e1 * r4.y + e2 * r4.z + e3 * r4.w;
        }
    }
    s  += __shfl_xor(s, 32);
    lg += __shfl_xor(lg, 32);
    rg += __shfl_xor(rg, 32);

    if (half == 0) {
        logits[b * LL + l0 + ln] = lg / s + sb;
        out_reuse[b * LL + l0 + ln] = rg / s + rb;
    }
}

// -------------------------------------- masked softmax over L per batch
__global__ void finalsm_kernel(const float* __restrict__ logits,
                               const int* __restrict__ lengths,
                               float* __restrict__ out_probs) {
    int b = blockIdx.x;
    int tid = threadIdx.x;
    int valid = max(lengths[b], 1);
    float v[4];
    float m = -1e30f;
#pragma unroll
    for (int i = 0; i < 4; ++i) {
        int l = tid + 256 * i;
        v[i] = (l < valid) ? logits[b * LL + l] : -1e30f;
        m = fmaxf(m, v[i]);
    }
#pragma unroll
    for (int off = 1; off < 64; off <<= 1) m = fmaxf(m, __shfl_xor(m, off));
    __shared__ float redm[4];
    __shared__ float reds[4];
    int wave = tid >> 6;
    if ((tid & 63) == 0) redm[wave] = m;
    __syncthreads();
    m = fmaxf(fmaxf(redm[0], redm[1]), fmaxf(redm[2], redm[3]));
    float e[4];
    float s = 0.f;
#pragma unroll
    for (int i = 0; i < 4; ++i) {
        int l = tid + 256 * i;
        e[i] = (l < valid) ? expf(v[i] - m) : 0.f;
        s += e[i];
    }
#pragma unroll
    for (int off = 1; off < 64; off <<= 1) s += __shfl_xor(s, off);
    if ((tid & 63) == 0) reds[wave] = s;
    __syncthreads();
    s = reds[0] + reds[1] + reds[2] + reds[3];
    float inv = 1.f / s;
#pragma unroll
    for (int i = 0; i < 4; ++i)
        out_probs[b * LL + tid + 256 * i] = e[i] * inv;
}

extern "C" void kernel_launch(void* const* d_in, const int* in_sizes, int n_in,
                              void* d_out, int out_size, void* d_ws, size_t ws_size,
                              hipStream_t stream) {
    const int*   obj_id         = (const int*)d_in[0];
    const int*   obj_size       = (const int*)d_in[1];
    const int*   cache_lines    = (const int*)d_in[2];
    const int*   lengths        = (const int*)d_in[3];
    const float* c0             = (const float*)d_in[4];
    const float* h0             = (const float*)d_in[5];
    const float* history        = (const float*)d_in[6];
    const float* obj_id_table   = (const float*)d_in[7];
    const float* obj_size_table = (const float*)d_in[8];
    const float* pos_table      = (const float*)d_in[9];
    const float* W_ih           = (const float*)d_in[10];
    const float* W_hh           = (const float*)d_in[11];
    const float* b_ih           = (const float*)d_in[12];
    const float* b_hh           = (const float*)d_in[13];
    const float* attn_W         = (const float*)d_in[14];
    const float* scorer_W       = (const float*)d_in[15];
    const float* scorer_b       = (const float*)d_in[16];
    const float* reuse_W        = (const float*)d_in[17];
    const float* reuse_b        = (const float*)d_in[18];

    float* out = (float*)d_out;
    float* out_probs = out;                 // (B, L)
    float* out_reuse = out + BB * LL;       // (B, L)

    char* ws = (char*)d_ws;
    float*          h_new  = (float*)(ws);                     // 64 KB
    unsigned short* hpF    = (unsigned short*)(ws + 65536);    // 2 MB bf16 (frag-major)
    float*          sv     = (float*)(ws + 2162688);           // 32 KB
    float*          rv     = (float*)(ws + 2195456);           // 32 KB
    float*          xh_t   = (float*)(ws + 2228224);           // 112 KB
    float*          logits = (float*)(ws + 2228224);           // shares xh_t (disjoint lifetime)
    unsigned short* qG     = (unsigned short*)(ws + 4194304);  // 16 MB (frag-ordered Q)

    // N1: embed (R0)
    hipLaunchKernelGGL(embed_kernel, dim3(112), dim3(256), 0, stream,
                       obj_id, obj_size, h0, obj_id_table, obj_size_table, xh_t);
    // N2: gates (R0)
    hipLaunchKernelGGL(gates_kernel, dim3(HH), dim3(256), 0, stream,
                       xh_t, W_ih, W_hh, b_ih, b_hh, c0, h_new);
    // N3: qgather ∥ proj ∥ svrv (mutual latency hiding, ~13 waves/CU)
    hipLaunchKernelGGL(proj_kernel, dim3(3328), dim3(64), 0, stream,
                       cache_lines, obj_id_table, history, h_new, attn_W,
                       pos_table, scorer_W, reuse_W, qG, hpF, sv, rv);
    // N4: attn (pure streaming from qG + hpF)
    hipLaunchKernelGGL(attn_kernel, dim3(BB * 32), dim3(64), 0, stream,
                       qG, hpF, sv, rv, scorer_b, reuse_b, logits, out_reuse);
    // N5: masked softmax
    hipLaunchKernelGGL(finalsm_kernel, dim3(BB), dim3(256), 0, stream,
                       logits, lengths, out_probs);
}